// Round 1
// baseline (2823.767 us; speedup 1.0000x reference)
//
#include <hip/hip_runtime.h>

// Problem constants (fixed by setup_inputs)
#define BB 4
#define HH 256
#define WW 512
#define LL 21
#define NEL (BB*HH*WW*LL)   // 11,010,048 elements per field
#define NDIR 4

// ---------------------------------------------------------------------------
// Elementwise: out = phi*scale + msgs[0] + msgs[1] + msgs[2] + msgs[3]
// scale=1 -> "total" for the next sweep; scale=2 -> final unary belief.
// NEL divisible by 4 -> exact float4 grid.
// ---------------------------------------------------------------------------
__global__ __launch_bounds__(256) void ewise_kernel(
    const float* __restrict__ phi, const float* __restrict__ msgs,
    float* __restrict__ out, float scale)
{
    int i = blockIdx.x * 256 + threadIdx.x;
    const float4* p4 = (const float4*)phi;
    const float4* m0 = (const float4*)(msgs + 0 * NEL);
    const float4* m1 = (const float4*)(msgs + 1 * NEL);
    const float4* m2 = (const float4*)(msgs + 2 * NEL);
    const float4* m3 = (const float4*)(msgs + 3 * NEL);
    float4 a = p4[i];
    float4 b0 = m0[i], b1 = m1[i], b2 = m2[i], b3 = m3[i];
    float4 r;
    r.x = a.x * scale + b0.x + b1.x + b2.x + b3.x;
    r.y = a.y * scale + b0.y + b1.y + b2.y + b3.y;
    r.z = a.z * scale + b0.z + b1.z + b2.z + b3.z;
    r.w = a.w * scale + b0.w + b1.w + b2.w + b3.w;
    ((float4*)out)[i] = r;
}

// ---------------------------------------------------------------------------
// Directional sweep, all 4 directions in one launch.
// Line q in [0,6144): d0 L->R (q<1024), d1 R->L (<2048), d2 T->B (<4096),
// d3 B->T. One 32-lane group per line (lane = output label), 8 lines/block.
// In-place msg update: at step s read old msg(s) (prefetched at s-1) before
// writing new m(s).
// Recurrence (matches reference _sweep):
//   m_0 = 0;  t_s(l) = total_s(l) - msgold_s(l) + m_s(l)
//   m_{s+1}(l') = min_l(t_s(l) + ctx(l,l')) - min_l(t_s(l) + rowmin(l))
// where rowmin(l) = min_{l'} ctx(l,l') equals the normalization min exactly.
// ---------------------------------------------------------------------------
__global__ __launch_bounds__(256) void sweep_kernel(
    const float* __restrict__ tot, const float* __restrict__ ctx,
    float* __restrict__ msgs, int first)
{
    __shared__ float sh[8][32];   // one 128B row per group, 16B-aligned

    const int tid  = threadIdx.x;
    const int g    = tid >> 5;
    const int lane = tid & 31;
    const int q    = blockIdx.x * 8 + g;

    int d, S, stride;
    int base;
    if (q < 2048) {                       // horizontal sweeps
        d = q >> 10;                      // 0 or 1
        int q2 = q & 1023;                // (b,h) line, b*HH+h == q2
        S = WW;
        base = q2 * (WW * LL);
        stride = LL;
        if (d == 1) { base += (WW - 1) * LL; stride = -LL; }
    } else {                              // vertical sweeps
        int qq = q - 2048;
        d = 2 + (qq >> 11);               // 2 or 3
        int q2 = qq & 2047;               // (b,w) line
        int b = q2 >> 9, w = q2 & 511;
        S = HH;
        base = (b * HH * WW + w) * LL;
        stride = WW * LL;
        if (d == 3) { base += (HH - 1) * WW * LL; stride = -stride; }
    }

    const float* ctxd = ctx + d * (LL * LL);

    // Per-lane context column: ctxcol[l] = ctx(l, lane). Inactive lanes get a
    // huge sentinel so their m_new stays large and harmless.
    float ctxcol[LL];
    #pragma unroll
    for (int l = 0; l < LL; ++l)
        ctxcol[l] = (lane < LL) ? ctxd[l * LL + lane] : 1e30f;

    // Uniform row minima (scalar-load territory; one-time cost per block).
    float rowmin[LL];
    #pragma unroll
    for (int l = 0; l < LL; ++l) {
        float mn = ctxd[l * LL + 0];
        #pragma unroll
        for (int j = 1; j < LL; ++j) mn = fminf(mn, ctxd[l * LL + j]);
        rowmin[l] = mn;
    }

    const bool act = (lane < LL);
    const int  ll  = act ? lane : (LL - 1);   // clamp inactive lanes in-bounds

    const float* tp = tot + base + ll;
    float*       mp = msgs + d * NEL + base + ll;

    float m   = 0.f;
    float tc  = tp[0];
    float moc = first ? 0.f : mp[0];

    for (int s = 0; s < S; ++s) {
        // distance-1 prefetch of next position (reads OLD msg before it is
        // overwritten at step s+1)
        float tn = 0.f, mon = 0.f;
        if (s + 1 < S) {
            tn = tp[stride];
            if (!first) mon = mp[stride];
        }

        float t = tc - moc + m;

        if (act) *mp = m;                 // write m_s (old msg(s) already consumed)

        // broadcast t across the group's 21 lanes via private LDS row
        sh[g][lane] = t;
        __builtin_amdgcn_wave_barrier();  // keep compiler from migrating the reads
        const float4* shp = (const float4*)(&sh[g][0]);
        float4 v0 = shp[0], v1 = shp[1], v2 = shp[2], v3 = shp[3], v4 = shp[4];
        float tv[LL] = { v0.x, v0.y, v0.z, v0.w,
                         v1.x, v1.y, v1.z, v1.w,
                         v2.x, v2.y, v2.z, v2.w,
                         v3.x, v3.y, v3.z, v3.w,
                         v4.x, v4.y, v4.z, v4.w,
                         sh[g][20] };

        // min-plus + fused normalization minimum
        float mn = 1e30f, gm = 1e30f;
        #pragma unroll
        for (int l = 0; l < LL; ++l) {
            mn = fminf(mn, tv[l] + ctxcol[l]);
            gm = fminf(gm, tv[l] + rowmin[l]);
        }
        m = mn - gm;

        tp += stride;
        mp += stride;
        tc = tn;
        moc = mon;
    }
}

// ---------------------------------------------------------------------------
extern "C" void kernel_launch(void* const* d_in, const int* in_sizes, int n_in,
                              void* d_out, int out_size, void* d_ws, size_t ws_size,
                              hipStream_t stream)
{
    (void)in_sizes; (void)n_in; (void)out_size; (void)ws_size;

    const float* phi = (const float*)d_in[0];
    const float* ctx = (const float*)d_in[1];   // [4,21,21]
    float* out  = (float*)d_out;                // doubles as "total" scratch
    float* msgs = (float*)d_ws;                 // 4 * NEL floats, updated in place

    const int EW_BLOCKS = NEL / 4 / 256;        // 10752, exact
    const int SW_BLOCKS = 6144 / 8;             // 768

    // iteration 1: total == phi, old msgs == 0 (never read -> poison-safe)
    sweep_kernel<<<SW_BLOCKS, 256, 0, stream>>>(phi, ctx, msgs, 1);

    for (int it = 1; it < 5; ++it) {
        ewise_kernel<<<EW_BLOCKS, 256, 0, stream>>>(phi, msgs, out, 1.0f);
        sweep_kernel<<<SW_BLOCKS, 256, 0, stream>>>(out, ctx, msgs, 0);
    }

    // final belief: phi*GAMMA_MNODE + sum of messages
    ewise_kernel<<<EW_BLOCKS, 256, 0, stream>>>(phi, msgs, out, 2.0f);
}

// Round 2
// 1514.424 us; speedup vs baseline: 1.8646x; 1.8646x over previous
//
#include <hip/hip_runtime.h>

// Problem constants (fixed by setup_inputs)
#define BB 4
#define HH 256
#define WW 512
#define LL 21
#define NEL (BB*HH*WW*LL)   // 11,010,048 elements per field
#define NDIR 4
#define PD 4                // global->reg prefetch distance (steps)

// ---------------------------------------------------------------------------
// Elementwise: out = phi*scale + msgs[0] + msgs[1] + msgs[2] + msgs[3]
// scale=1 -> "total" for the next sweep; scale=2 -> final unary belief.
// ---------------------------------------------------------------------------
__global__ __launch_bounds__(256) void ewise_kernel(
    const float* __restrict__ phi, const float* __restrict__ msgs,
    float* __restrict__ out, float scale)
{
    int i = blockIdx.x * 256 + threadIdx.x;
    const float4* p4 = (const float4*)phi;
    const float4* m0 = (const float4*)(msgs + 0 * NEL);
    const float4* m1 = (const float4*)(msgs + 1 * NEL);
    const float4* m2 = (const float4*)(msgs + 2 * NEL);
    const float4* m3 = (const float4*)(msgs + 3 * NEL);
    float4 a = p4[i];
    float4 b0 = m0[i], b1 = m1[i], b2 = m2[i], b3 = m3[i];
    float4 r;
    r.x = a.x * scale + b0.x + b1.x + b2.x + b3.x;
    r.y = a.y * scale + b0.y + b1.y + b2.y + b3.y;
    r.z = a.z * scale + b0.z + b1.z + b2.z + b3.z;
    r.w = a.w * scale + b0.w + b1.w + b2.w + b3.w;
    ((float4*)out)[i] = r;
}

// ---------------------------------------------------------------------------
// Directional sweep, all 4 directions in one launch.
// One 32-lane group per scanline (lane = output label), 8 lines/block.
// In-place msg update: reads of msg(s+PD) strictly precede the write of
// msg(s), so the PD-deep prefetch FIFO is hazard-free.
//
// General recurrence (matches reference _sweep):
//   m_0 = 0;  t_s(l) = total_s(l) - msgold_s(l) + m_s(l)
//   m_{s+1}(l') = min_l(t_s(l) + ctx(l,l')) - min_l(t_s(l) + rowmin(l))
// Potts fast path (ctx = c*(1-delta), c>=0, detected at runtime):
//   m_{s+1}(l') = min(t_s(l') - tmin, c)   [algebraically exact, ties incl.]
// ---------------------------------------------------------------------------
__global__ __launch_bounds__(256) void sweep_kernel(
    const float* __restrict__ tot, const float* __restrict__ ctx,
    float* __restrict__ msgs, int first)
{
    __shared__ float sh[8][32];   // one 128B row per group

    const int tid  = threadIdx.x;
    const int g    = tid >> 5;
    const int lane = tid & 31;
    const int q    = blockIdx.x * 8 + g;

    int d, S, stride, base;
    if (q < 2048) {                       // horizontal sweeps
        d = q >> 10;                      // 0 or 1
        int q2 = q & 1023;                // (b,h) line
        S = WW;
        base = q2 * (WW * LL);
        stride = LL;
        if (d == 1) { base += (WW - 1) * LL; stride = -LL; }
    } else {                              // vertical sweeps
        int qq = q - 2048;
        d = 2 + (qq >> 11);               // 2 or 3
        int q2 = qq & 2047;               // (b,w) line
        int b = q2 >> 9, w = q2 & 511;
        S = HH;
        base = (b * HH * WW + w) * LL;
        stride = WW * LL;
        if (d == 3) { base += (HH - 1) * WW * LL; stride = -stride; }
    }

    const float* ctxd = ctx + d * (LL * LL);
    const float  c    = ctxd[1];          // candidate Potts constant (uniform)

    // Per-lane context column: ctxcol[l] = ctx(l, lane).
    float ctxcol[LL];
    #pragma unroll
    for (int l = 0; l < LL; ++l)
        ctxcol[l] = (lane < LL) ? ctxd[l * LL + lane] : 1e30f;

    // Runtime Potts detection (both groups in a wave share d -> wave-uniform).
    bool bad = false;
    if (lane < LL) {
        #pragma unroll
        for (int l = 0; l < LL; ++l) {
            float want = (l == lane) ? 0.f : c;
            bad |= (ctxcol[l] != want);
        }
    }
    const bool potts = (__ballot(bad) == 0ull) && (c >= 0.f);

    const bool act = (lane < LL);
    const int  ll  = act ? lane : (LL - 1);

    const float* tp  = tot  + base + ll;
    const float* mrd = msgs + (size_t)d * NEL + base + ll;
    float*       mwr = msgs + (size_t)d * NEL + base + ll;

    // prefetch FIFO, depth PD (S >= 256 >> PD, so no guards needed here)
    float tf0 = tp[0],          mf0 = first ? 0.f : mrd[0];
    float tf1 = tp[stride],     mf1 = first ? 0.f : mrd[stride];
    float tf2 = tp[2 * stride], mf2 = first ? 0.f : mrd[2 * stride];
    float tf3 = tp[3 * stride], mf3 = first ? 0.f : mrd[3 * stride];
    const float* tpp = tp  + PD * stride;
    const float* mpp = mrd + PD * stride;

    float m = 0.f;

    if (potts) {
        for (int s = 0; s < S; ++s) {
            float tc = tf0, moc = mf0;
            tf0 = tf1; tf1 = tf2; tf2 = tf3;
            mf0 = mf1; mf1 = mf2; mf2 = mf3;
            bool inb = (s + PD) < S;
            tf3 = inb ? *tpp : 0.f;
            mf3 = (inb && !first) ? *mpp : 0.f;
            tpp += stride; mpp += stride;

            float t = tc - moc + m;
            if (act) *mwr = m;
            mwr += stride;

            __builtin_amdgcn_wave_barrier();
            sh[g][lane] = act ? t : 1e30f;
            __builtin_amdgcn_wave_barrier();
            const float4* shp = (const float4*)(&sh[g][0]);
            float4 v0 = shp[0], v1 = shp[1], v2 = shp[2], v3 = shp[3], v4 = shp[4];
            float w20 = sh[g][20];

            float a2 = fminf(fminf(v0.x, v0.y), fminf(v0.z, v0.w));
            float b2 = fminf(fminf(v1.x, v1.y), fminf(v1.z, v1.w));
            float c2 = fminf(fminf(v2.x, v2.y), fminf(v2.z, v2.w));
            float d2 = fminf(fminf(v3.x, v3.y), fminf(v3.z, v3.w));
            float e2 = fminf(fminf(v4.x, v4.y), fminf(v4.z, v4.w));
            float tmin = fminf(fminf(fminf(a2, b2), fminf(c2, d2)),
                               fminf(e2, w20));
            m = fminf(t - tmin, c);
        }
    } else {
        // General min-plus path (correct for arbitrary ctx; not taken on the
        // bench input). rowmin forced uniform -> SGPRs via readfirstlane.
        float rowmin[LL];
        #pragma unroll
        for (int l = 0; l < LL; ++l) {
            float mn = ctxd[l * LL];
            #pragma unroll
            for (int j = 1; j < LL; ++j) mn = fminf(mn, ctxd[l * LL + j]);
            rowmin[l] = __int_as_float(
                __builtin_amdgcn_readfirstlane(__float_as_int(mn)));
        }
        for (int s = 0; s < S; ++s) {
            float tc = tf0, moc = mf0;
            tf0 = tf1; tf1 = tf2; tf2 = tf3;
            mf0 = mf1; mf1 = mf2; mf2 = mf3;
            bool inb = (s + PD) < S;
            tf3 = inb ? *tpp : 0.f;
            mf3 = (inb && !first) ? *mpp : 0.f;
            tpp += stride; mpp += stride;

            float t = tc - moc + m;
            if (act) *mwr = m;
            mwr += stride;

            __builtin_amdgcn_wave_barrier();
            sh[g][lane] = act ? t : 1e30f;
            __builtin_amdgcn_wave_barrier();
            const float4* shp = (const float4*)(&sh[g][0]);
            float4 v0 = shp[0], v1 = shp[1], v2 = shp[2], v3 = shp[3], v4 = shp[4];
            float tv[LL] = { v0.x, v0.y, v0.z, v0.w,
                             v1.x, v1.y, v1.z, v1.w,
                             v2.x, v2.y, v2.z, v2.w,
                             v3.x, v3.y, v3.z, v3.w,
                             v4.x, v4.y, v4.z, v4.w,
                             sh[g][20] };
            // pairwise trees to keep the dependence depth ~log2(21)
            float mn0[LL], gm0[LL];
            #pragma unroll
            for (int l = 0; l < LL; ++l) {
                mn0[l] = tv[l] + ctxcol[l];
                gm0[l] = tv[l] + rowmin[l];
            }
            float mn = mn0[20], gmv = gm0[20];
            #pragma unroll
            for (int l = 0; l < 10; ++l) {
                mn  = fminf(mn,  fminf(mn0[2*l], mn0[2*l+1]));
                gmv = fminf(gmv, fminf(gm0[2*l], gm0[2*l+1]));
            }
            m = mn - gmv;
        }
    }
}

// ---------------------------------------------------------------------------
extern "C" void kernel_launch(void* const* d_in, const int* in_sizes, int n_in,
                              void* d_out, int out_size, void* d_ws, size_t ws_size,
                              hipStream_t stream)
{
    (void)in_sizes; (void)n_in; (void)out_size; (void)ws_size;

    const float* phi = (const float*)d_in[0];
    const float* ctx = (const float*)d_in[1];   // [4,21,21]
    float* out  = (float*)d_out;                // doubles as "total" scratch
    float* msgs = (float*)d_ws;                 // 4 * NEL floats, in-place

    const int EW_BLOCKS = NEL / 4 / 256;        // 10752, exact
    const int SW_BLOCKS = 6144 / 8;             // 768

    // iteration 1: total == phi, old msgs == 0 (never read -> poison-safe)
    sweep_kernel<<<SW_BLOCKS, 256, 0, stream>>>(phi, ctx, msgs, 1);

    for (int it = 1; it < 5; ++it) {
        ewise_kernel<<<EW_BLOCKS, 256, 0, stream>>>(phi, msgs, out, 1.0f);
        sweep_kernel<<<SW_BLOCKS, 256, 0, stream>>>(out, ctx, msgs, 0);
    }

    // final belief: phi*GAMMA_MNODE + sum of messages
    ewise_kernel<<<EW_BLOCKS, 256, 0, stream>>>(phi, msgs, out, 2.0f);
}

// Round 3
// 886.732 us; speedup vs baseline: 3.1845x; 1.7079x over previous
//
#include <hip/hip_runtime.h>

// Problem constants (fixed by setup_inputs)
#define BB 4
#define HH 256
#define WW 512
#define LL 21
#define NEL (BB*HH*WW*LL)   // 11,010,048 elements per field
#define NDIR 4
#define PD 4                // global->reg prefetch distance (steps)

// ---------------------------------------------------------------------------
// Elementwise: out = phi*scale + msgs[0] + msgs[1] + msgs[2] + msgs[3]
// ---------------------------------------------------------------------------
__global__ __launch_bounds__(256) void ewise_kernel(
    const float* __restrict__ phi, const float* __restrict__ msgs,
    float* __restrict__ out, float scale)
{
    int i = blockIdx.x * 256 + threadIdx.x;
    const float4* p4 = (const float4*)phi;
    const float4* m0 = (const float4*)(msgs + 0 * NEL);
    const float4* m1 = (const float4*)(msgs + 1 * NEL);
    const float4* m2 = (const float4*)(msgs + 2 * NEL);
    const float4* m3 = (const float4*)(msgs + 3 * NEL);
    float4 a = p4[i];
    float4 b0 = m0[i], b1 = m1[i], b2 = m2[i], b3 = m3[i];
    float4 r;
    r.x = a.x * scale + b0.x + b1.x + b2.x + b3.x;
    r.y = a.y * scale + b0.y + b1.y + b2.y + b3.y;
    r.z = a.z * scale + b0.z + b1.z + b2.z + b3.z;
    r.w = a.w * scale + b0.w + b1.w + b2.w + b3.w;
    ((float4*)out)[i] = r;
}

// ---------------------------------------------------------------------------
// 32-lane-group min, result broadcast to all lanes of the group.
// 4 DPP v_min (VALU pipe) + 1 ds_swizzle xor16 (bit-mode = per-32-lane).
// ---------------------------------------------------------------------------
__device__ __forceinline__ float dpp_min_step(float x, const int ctrl_b1,
                                              const int ctrl_4e,
                                              const int ctrl_hm,
                                              const int ctrl_m)
{
    // helper unused; kept for clarity of constants
    return x;
}

__device__ __forceinline__ float group32_min(float x)
{
    int xi = __float_as_int(x);
    int y;
    y  = __builtin_amdgcn_update_dpp(xi, xi, 0xB1, 0xf, 0xf, false); // quad_perm(1,0,3,2): xor1
    x  = fminf(x, __int_as_float(y)); xi = __float_as_int(x);
    y  = __builtin_amdgcn_update_dpp(xi, xi, 0x4E, 0xf, 0xf, false); // quad_perm(2,3,0,1): xor2
    x  = fminf(x, __int_as_float(y)); xi = __float_as_int(x);
    y  = __builtin_amdgcn_update_dpp(xi, xi, 0x141, 0xf, 0xf, false); // row_half_mirror
    x  = fminf(x, __int_as_float(y)); xi = __float_as_int(x);
    y  = __builtin_amdgcn_update_dpp(xi, xi, 0x140, 0xf, 0xf, false); // row_mirror
    x  = fminf(x, __int_as_float(y)); xi = __float_as_int(x);
    y  = __builtin_amdgcn_ds_swizzle(xi, 0x401F);                    // xor16 (32-lane grp)
    x  = fminf(x, __int_as_float(y));
    return x;
}

// ---------------------------------------------------------------------------
// Directional sweep, all 4 directions in one launch.
// One 32-lane group per scanline (lane = output label), 8 lines/block.
// In-place msg update: reads of msg(s+PD) strictly precede the write of
// msg(s) -> hazard-free with the PD-deep register FIFO.
//
// Potts fast path (unnormalized form, exact):
//   T_0(l) = u_0(l);   Tmin_s = min_l T_s(l);   Q_s = Tmin_s + c
//   T_{s+1}(l) = u_{s+1}(l) + min(T_s(l), Q_s)
//   message written at s+1:  m_{s+1}(l) = min(T_s(l), Q_s) - Tmin_s
// General path (arbitrary ctx): LDS broadcast min-plus (correct, slow).
// ---------------------------------------------------------------------------
template<bool FIRST>
__global__ __launch_bounds__(256) void sweep_kernel(
    const float* __restrict__ tot, const float* __restrict__ ctx,
    float* __restrict__ msgs)
{
    __shared__ float sh[8][32];   // used only by the general path

    const int tid  = threadIdx.x;
    const int g    = tid >> 5;
    const int lane = tid & 31;
    const int q    = blockIdx.x * 8 + g;

    int d, S, stride, base;
    if (q < 2048) {                       // horizontal sweeps
        d = q >> 10;                      // 0 or 1
        int q2 = q & 1023;                // (b,h) line
        S = WW;
        base = q2 * (WW * LL);
        stride = LL;
        if (d == 1) { base += (WW - 1) * LL; stride = -LL; }
    } else {                              // vertical sweeps
        int qq = q - 2048;
        d = 2 + (qq >> 11);               // 2 or 3
        int q2 = qq & 2047;               // (b,w) line
        int b = q2 >> 9, w = q2 & 511;
        S = HH;
        base = (b * HH * WW + w) * LL;
        stride = WW * LL;
        if (d == 3) { base += (HH - 1) * WW * LL; stride = -stride; }
    }

    const float* ctxd = ctx + d * (LL * LL);
    const float  c    = ctxd[1];          // candidate Potts constant

    // Per-lane context column (needed for Potts check + general path)
    float ctxcol[LL];
    #pragma unroll
    for (int l = 0; l < LL; ++l)
        ctxcol[l] = (lane < LL) ? ctxd[l * LL + lane] : 1e30f;

    bool bad = false;
    if (lane < LL) {
        #pragma unroll
        for (int l = 0; l < LL; ++l) {
            float want = (l == lane) ? 0.f : c;
            bad |= (ctxcol[l] != want);
        }
    }
    const bool potts = (__ballot(bad) == 0ull) && (c >= 0.f);

    const bool act = (lane < LL);
    const int  ll  = act ? lane : (LL - 1);

    const float* tp  = tot  + base + ll;
    const float* mrd = msgs + (size_t)d * NEL + base + ll;
    float*       mwr = msgs + (size_t)d * NEL + base + ll;

    // register prefetch FIFO, depth PD=4
    float t0 = tp[0],          t1 = tp[stride],
          t2 = tp[2 * stride], t3 = tp[3 * stride];
    float f0 = FIRST ? 0.f : mrd[0],          f1 = FIRST ? 0.f : mrd[stride],
          f2 = FIRST ? 0.f : mrd[2 * stride], f3 = FIRST ? 0.f : mrd[3 * stride];
    const float* tld = tp  + PD * stride;
    const float* mld = mrd + PD * stride;
    float* mw = mwr;

    if (potts) {
        float mn_prev = 0.f, tmin_prev = 0.f;  // -> m_0 = 0

        auto step = [&](float tc, float mo) {
            if (act) *mw = mn_prev - tmin_prev;     // write m_s
            mw += stride;
            float T  = (tc - mo) + mn_prev;         // T_s = u_s + min(T_{s-1},Q)
            float Tr = act ? T : 1e30f;
            float tmin = group32_min(Tr);
            mn_prev   = fminf(T, tmin + c);
            tmin_prev = tmin;
        };

        // main loop: unconditional prefetch, (S-PD) divisible by 4
        for (int s4 = 0; s4 < S - PD; s4 += 4) {
            { float tc = t0, mo = f0; t0 = *tld; tld += stride;
              if (!FIRST) { f0 = *mld; } mld += stride; step(tc, mo); }
            { float tc = t1, mo = f1; t1 = *tld; tld += stride;
              if (!FIRST) { f1 = *mld; } mld += stride; step(tc, mo); }
            { float tc = t2, mo = f2; t2 = *tld; tld += stride;
              if (!FIRST) { f2 = *mld; } mld += stride; step(tc, mo); }
            { float tc = t3, mo = f3; t3 = *tld; tld += stride;
              if (!FIRST) { f3 = *mld; } mld += stride; step(tc, mo); }
        }
        // epilogue: drain FIFO
        step(t0, f0); step(t1, f1); step(t2, f2); step(t3, f3);
    } else {
        // General min-plus path (correct for arbitrary ctx; not taken on the
        // bench input).
        float rowmin[LL];
        #pragma unroll
        for (int l = 0; l < LL; ++l) {
            float mn = ctxd[l * LL];
            #pragma unroll
            for (int j = 1; j < LL; ++j) mn = fminf(mn, ctxd[l * LL + j]);
            rowmin[l] = __int_as_float(
                __builtin_amdgcn_readfirstlane(__float_as_int(mn)));
        }
        float m = 0.f;
        auto step = [&](float tc, float mo) {
            float t = tc - mo + m;
            if (act) *mw = m;
            mw += stride;
            __builtin_amdgcn_wave_barrier();
            sh[g][lane] = act ? t : 1e30f;
            __builtin_amdgcn_wave_barrier();
            const float4* shp = (const float4*)(&sh[g][0]);
            float4 v0 = shp[0], v1 = shp[1], v2 = shp[2], v3 = shp[3], v4 = shp[4];
            float tv[LL] = { v0.x, v0.y, v0.z, v0.w,
                             v1.x, v1.y, v1.z, v1.w,
                             v2.x, v2.y, v2.z, v2.w,
                             v3.x, v3.y, v3.z, v3.w,
                             v4.x, v4.y, v4.z, v4.w,
                             sh[g][20] };
            float mn0[LL], gm0[LL];
            #pragma unroll
            for (int l = 0; l < LL; ++l) {
                mn0[l] = tv[l] + ctxcol[l];
                gm0[l] = tv[l] + rowmin[l];
            }
            float mn = mn0[20], gmv = gm0[20];
            #pragma unroll
            for (int l = 0; l < 10; ++l) {
                mn  = fminf(mn,  fminf(mn0[2*l], mn0[2*l+1]));
                gmv = fminf(gmv, fminf(gm0[2*l], gm0[2*l+1]));
            }
            m = mn - gmv;
        };
        for (int s4 = 0; s4 < S - PD; s4 += 4) {
            { float tc = t0, mo = f0; t0 = *tld; tld += stride;
              if (!FIRST) { f0 = *mld; } mld += stride; step(tc, mo); }
            { float tc = t1, mo = f1; t1 = *tld; tld += stride;
              if (!FIRST) { f1 = *mld; } mld += stride; step(tc, mo); }
            { float tc = t2, mo = f2; t2 = *tld; tld += stride;
              if (!FIRST) { f2 = *mld; } mld += stride; step(tc, mo); }
            { float tc = t3, mo = f3; t3 = *tld; tld += stride;
              if (!FIRST) { f3 = *mld; } mld += stride; step(tc, mo); }
        }
        step(t0, f0); step(t1, f1); step(t2, f2); step(t3, f3);
    }
}

// ---------------------------------------------------------------------------
extern "C" void kernel_launch(void* const* d_in, const int* in_sizes, int n_in,
                              void* d_out, int out_size, void* d_ws, size_t ws_size,
                              hipStream_t stream)
{
    (void)in_sizes; (void)n_in; (void)out_size; (void)ws_size;

    const float* phi = (const float*)d_in[0];
    const float* ctx = (const float*)d_in[1];   // [4,21,21]
    float* out  = (float*)d_out;                // doubles as "total" scratch
    float* msgs = (float*)d_ws;                 // 4 * NEL floats, in-place

    const int EW_BLOCKS = NEL / 4 / 256;        // 10752, exact
    const int SW_BLOCKS = 6144 / 8;             // 768

    // iteration 1: total == phi, old msgs == 0 (never read -> poison-safe)
    sweep_kernel<true><<<SW_BLOCKS, 256, 0, stream>>>(phi, ctx, msgs);

    for (int it = 1; it < 5; ++it) {
        ewise_kernel<<<EW_BLOCKS, 256, 0, stream>>>(phi, msgs, out, 1.0f);
        sweep_kernel<false><<<SW_BLOCKS, 256, 0, stream>>>(out, ctx, msgs);
    }

    // final belief: phi*GAMMA_MNODE + sum of messages
    ewise_kernel<<<EW_BLOCKS, 256, 0, stream>>>(phi, msgs, out, 2.0f);
}